// Round 5
// baseline (370.068 us; speedup 1.0000x reference)
//
#include <hip/hip_runtime.h>
#include <math.h>

// Linear attention forward. bf16 MFMA + zero-VGPR global_load_lds fp32 staging.
// B=8, L=S=8192, D=256, H=8, hd=32.
// kPrep: W -> bf16 fragment-major Wf in ws.
// kA: 32-token tiles; K/V proj MFMA (fp32 LDS + v_cvt_pk_bf16_f32 at frag read);
//     elu+1/mask epilogue -> in-register frags -> KV/Ksum partials.
// kR: reduce partials. kB: Q proj (flipped) + num/Z + out GEMM.

#define B_ 8
#define S_ 8192
#define D_ 256
#define H_ 8
#define EPS_ 1e-6f

typedef short short8 __attribute__((ext_vector_type(8)));
typedef float f32x16 __attribute__((ext_vector_type(16)));

// kA LDS: bufX fp32 tile 32KB | masks 512B
#define KA_X 0
#define KA_M 32768
#define KA_BYTES 33280
// kB LDS: bufQ 32KB | ldsO (vo bf16) 16KB | mask 128B | Ksum 1KB | bq 1KB
#define KB_Q 0
#define KB_O 32768
#define KB_M 49152
#define KB_S 49280
#define KB_BQ 50304
#define KB_BYTES 51328

static __device__ __forceinline__ unsigned short f2bf(float f) {
  union { float f; unsigned u; } v; v.f = f;
  return (unsigned short)((v.u + 0x7fffu + ((v.u >> 16) & 1u)) >> 16);
}
static __device__ __forceinline__ unsigned pack2(float a, float b) {
  return (unsigned)f2bf(a) | ((unsigned)f2bf(b) << 16);
}
// HW packed fp32->bf16 (RNE): low16 = bf16(a), high16 = bf16(b).
static __device__ __forceinline__ unsigned cvt_pk(float a, float b) {
  unsigned r;
  asm("v_cvt_pk_bf16_f32 %0, %1, %2" : "=v"(r) : "v"(a), "v"(b));
  return r;
}

typedef __attribute__((address_space(1))) const void GV;
typedef __attribute__((address_space(3))) void LV;
static __device__ __forceinline__ void gll16(const void* gp, void* lp) {
  __builtin_amdgcn_global_load_lds((GV*)gp, (LV*)lp, 16, 0, 0);
}

// Issue one 32x256 fp32 tile: row r (1KB) per wave-instr, source pre-swizzled
// by chunk c -> c ^ (r&15) so the linear LDS row is XOR-permuted (involution).
static __device__ __forceinline__ void issue_tile(const float* __restrict__ src,
                                                  char* __restrict__ buf,
                                                  int w, int lane) {
#pragma unroll
  for (int i = 0; i < 8; ++i) {
    const int r = w * 8 + i;
    const float* gp = src + r * 256 + ((lane ^ (r & 15)) << 2);
    gll16((const void*)gp, (void*)(buf + r * 1024));
  }
}

// Read bf16x8 fragment = X[row][g*8 .. g*8+7] from swizzled fp32 LDS tile.
static __device__ __forceinline__ short8 ld_frag_f32(const char* __restrict__ ldsX,
                                                     int row, int g) {
  const int s0 = (g * 2) ^ (row & 15);
  const int s1 = (g * 2 + 1) ^ (row & 15);
  float4 a = *(const float4*)(ldsX + row * 1024 + s0 * 16);
  float4 b = *(const float4*)(ldsX + row * 1024 + s1 * 16);
  union { unsigned u[4]; short8 s8; } t;
  t.u[0] = cvt_pk(a.x, a.y);
  t.u[1] = cvt_pk(a.z, a.w);
  t.u[2] = cvt_pk(b.x, b.y);
  t.u[3] = cvt_pk(b.z, b.w);
  return t.s8;
}

// Build MFMA A/B fragment (k = 8*kg + j within a 16-slice) from epilogue words.
static __device__ __forceinline__ short8 mk_frag(unsigned w00, unsigned w01,
                                                 unsigned w10, unsigned w11, int kg) {
  unsigned a0 = kg ? w10 : w00, a1 = kg ? w11 : w01;
  unsigned s0 = kg ? w00 : w10, s1 = kg ? w01 : w11;
  unsigned r0 = __shfl_xor(s0, 32), r1 = __shfl_xor(s1, 32);
  union { unsigned u[4]; short8 s8; } f;
  f.u[0] = kg ? r0 : a0; f.u[1] = kg ? r1 : a1;
  f.u[2] = kg ? a0 : r0; f.u[3] = kg ? a1 : r1;
  return f.s8;
}

__global__ void kPrep(const float* __restrict__ Wq, const float* __restrict__ Wk,
                      const float* __restrict__ Wv, const float* __restrict__ Wm,
                      unsigned short* __restrict__ Wf) {
  int idx = blockIdx.x * 256 + threadIdx.x;  // 32768 = 4*32*256
  int wsel = idx >> 13, g = (idx >> 8) & 31, o = idx & 255;
  const float* W = wsel == 0 ? Wq : wsel == 1 ? Wk : wsel == 2 ? Wv : Wm;
  const float* p = W + o * 256 + g * 8;
  *(ushort4*)(Wf + (size_t)idx * 8) =
      make_ushort4(f2bf(p[0]), f2bf(p[1]), f2bf(p[2]), f2bf(p[3]));
  *(ushort4*)(Wf + (size_t)idx * 8 + 4) =
      make_ushort4(f2bf(p[4]), f2bf(p[5]), f2bf(p[6]), f2bf(p[7]));
}

// kA: grid (64, B_), 256 thr; block processes 4 tiles of 32 tokens.
__global__ void __launch_bounds__(256, 3)
kA(const float* __restrict__ keys, const float* __restrict__ values,
   const float* __restrict__ kmask,
   const float* __restrict__ bk, const float* __restrict__ bv,
   const short8* __restrict__ WfK, const short8* __restrict__ WfV,
   float* __restrict__ kvpart, float* __restrict__ kspart,
   float* __restrict__ KV, float* __restrict__ Ksum, int use_atomic) {
  extern __shared__ char lds[];
  char* bufX = lds + KA_X;
  float* ldsM = (float*)(lds + KA_M);
  const int tid = threadIdx.x, w = tid >> 6, lane = tid & 63, lo = lane & 31, kg = lane >> 5;
  const int blk = blockIdx.x, b = blockIdx.y;
  const size_t base = ((size_t)b * S_ + blk * 128) * D_;

  const float bk0 = bk[w * 64 + lo], bk1 = bk[w * 64 + 32 + lo];
  const float bv0 = bv[w * 64 + lo], bv1 = bv[w * 64 + 32 + lo];

  f32x16 kvacc[2];
#pragma unroll
  for (int hh = 0; hh < 2; ++hh)
#pragma unroll
    for (int i = 0; i < 16; ++i) kvacc[hh][i] = 0.f;
  float ks0 = 0.f, ks1 = 0.f;

  if (tid < 128) ldsM[tid] = kmask[(size_t)b * S_ + blk * 128 + tid];
  issue_tile(keys + base, bufX, w, lane);  // K(0)

#pragma unroll 1
  for (int it = 0; it < 4; ++it) {
    __syncthreads();  // K(it) arrived (drains vmcnt), masks visible

    // ---- K projection: D[tok][o], tok rows = lo ----
    f32x16 acc[2];
#pragma unroll
    for (int nt = 0; nt < 2; ++nt)
#pragma unroll
      for (int i = 0; i < 16; ++i) acc[nt][i] = 0.f;
#pragma unroll 4
    for (int ks = 0; ks < 16; ++ks) {
      const int g = 2 * ks + kg;
      short8 af = ld_frag_f32(bufX, lo, g);
      short8 b0 = WfK[g * 256 + w * 64 + lo];
      short8 b1 = WfK[g * 256 + w * 64 + 32 + lo];
      acc[0] = __builtin_amdgcn_mfma_f32_32x32x16_bf16(af, b0, acc[0], 0, 0, 0);
      acc[1] = __builtin_amdgcn_mfma_f32_32x32x16_bf16(af, b1, acc[1], 0, 0, 0);
    }
    __syncthreads();           // all waves done reading bufX (K)
    issue_tile(values + base + (size_t)it * 32 * D_, bufX, w, lane);  // V(it) in flight

    // K epilogue under V flight: bias + elu+1 + mask -> words + Ksum
    unsigned Wk_[2][4][2];
#pragma unroll
    for (int nt = 0; nt < 2; ++nt) {
      const float bias = nt ? bk1 : bk0;
#pragma unroll
      for (int q = 0; q < 4; ++q) {
        float vv[4];
#pragma unroll
        for (int c = 0; c < 4; ++c) {
          const int tok = 8 * q + 4 * kg + c;
          float f = acc[nt][4 * q + c] + bias;
          f = f > 0.f ? f + 1.f : __expf(f);
          f *= ldsM[it * 32 + tok];
          if (nt == 0) ks0 += f; else ks1 += f;
          vv[c] = f;
        }
        Wk_[nt][q][0] = pack2(vv[0], vv[1]);
        Wk_[nt][q][1] = pack2(vv[2], vv[3]);
      }
    }
    short8 kf[2][2];
#pragma unroll
    for (int nt = 0; nt < 2; ++nt)
#pragma unroll
      for (int sel = 0; sel < 2; ++sel)
        kf[nt][sel] = mk_frag(Wk_[nt][2 * sel][0], Wk_[nt][2 * sel][1],
                              Wk_[nt][2 * sel + 1][0], Wk_[nt][2 * sel + 1][1], kg);

    __syncthreads();  // V(it) arrived

    // ---- V projection ----
#pragma unroll
    for (int nt = 0; nt < 2; ++nt)
#pragma unroll
      for (int i = 0; i < 16; ++i) acc[nt][i] = 0.f;
#pragma unroll 4
    for (int ks = 0; ks < 16; ++ks) {
      const int g = 2 * ks + kg;
      short8 af = ld_frag_f32(bufX, lo, g);
      short8 b0 = WfV[g * 256 + w * 64 + lo];
      short8 b1 = WfV[g * 256 + w * 64 + 32 + lo];
      acc[0] = __builtin_amdgcn_mfma_f32_32x32x16_bf16(af, b0, acc[0], 0, 0, 0);
      acc[1] = __builtin_amdgcn_mfma_f32_32x32x16_bf16(af, b1, acc[1], 0, 0, 0);
    }
    __syncthreads();          // all waves done reading bufX (V)
    if (it < 3) issue_tile(keys + base + (size_t)(it + 1) * 32 * D_, bufX, w, lane);

    // V epilogue + KV accumulate under K(it+1) flight
    unsigned Wv_[2][4][2];
#pragma unroll
    for (int nt = 0; nt < 2; ++nt) {
      const float bias = nt ? bv1 : bv0;
#pragma unroll
      for (int q = 0; q < 4; ++q) {
        float vv[4];
#pragma unroll
        for (int c = 0; c < 4; ++c) {
          const int tok = 8 * q + 4 * kg + c;
          vv[c] = (acc[nt][4 * q + c] + bias) * ldsM[it * 32 + tok];
        }
        Wv_[nt][q][0] = pack2(vv[0], vv[1]);
        Wv_[nt][q][1] = pack2(vv[2], vv[3]);
      }
    }
#pragma unroll
    for (int hh = 0; hh < 2; ++hh)
#pragma unroll
      for (int sel = 0; sel < 2; ++sel) {
        short8 vf = mk_frag(Wv_[hh][2 * sel][0], Wv_[hh][2 * sel][1],
                            Wv_[hh][2 * sel + 1][0], Wv_[hh][2 * sel + 1][1], kg);
        kvacc[hh] = __builtin_amdgcn_mfma_f32_32x32x16_bf16(kf[hh][sel], vf,
                                                            kvacc[hh], 0, 0, 0);
      }
  }

  // ---- flush ----
  const float tot0 = ks0 + __shfl_xor(ks0, 32);
  const float tot1 = ks1 + __shfl_xor(ks1, 32);
  if (use_atomic) {
    atomicAdd(&Ksum[b * 256 + w * 64 + kg * 32 + lo], kg ? tot1 : tot0);
#pragma unroll
    for (int hh = 0; hh < 2; ++hh) {
      const int h = 2 * w + hh;
#pragma unroll
      for (int r = 0; r < 16; ++r) {
        const int d = (r & 3) + 8 * (r >> 2) + 4 * kg;
        atomicAdd(&KV[(((size_t)b * H_ + h) * 32 + lo) * 32 + d], kvacc[hh][r]);
      }
    }
  } else {
    kspart[((size_t)b * 64 + blk) * 256 + w * 64 + kg * 32 + lo] = kg ? tot1 : tot0;
#pragma unroll
    for (int hh = 0; hh < 2; ++hh) {
      const int h = 2 * w + hh;
      float* dst = kvpart + ((size_t)b * 64 + blk) * 8192 + ((h * 2 + kg) * 16) * 32 + lo;
#pragma unroll
      for (int r = 0; r < 16; ++r) dst[r * 32] = kvacc[hh][r];
    }
  }
}

// kR: reduce 64 block-partials per batch. grid 264 x 256.
__global__ void kR(const float* __restrict__ kvpart, const float* __restrict__ kspart,
                   float* __restrict__ KV, float* __restrict__ Ksum) {
  int idx = blockIdx.x * 256 + threadIdx.x;
  if (idx < 65536) {
    int b = idx >> 13, r2 = idx & 8191;
    int h = r2 >> 10, kg2 = (r2 >> 9) & 1, rr = (r2 >> 5) & 15, m = r2 & 31;
    const float* p = kvpart + (size_t)b * 64 * 8192 + r2;
    float s = 0.f;
#pragma unroll 8
    for (int j = 0; j < 64; ++j) s += p[(size_t)j * 8192];
    int d = (rr & 3) + 4 * kg2 + 8 * (rr >> 2);
    KV[(((size_t)b * H_ + h) * 32 + m) * 32 + d] = s;
  } else if (idx < 67584) {
    int t = idx - 65536;
    int b = t >> 8, o = t & 255;
    const float* p = kspart + (size_t)b * 64 * 256 + o;
    float s = 0.f;
#pragma unroll 8
    for (int j = 0; j < 64; ++j) s += p[j * 256];
    Ksum[t] = s;
  }
}

// kB: grid (256, B_), 256 thr, one 32-token tile per block.
__global__ void __launch_bounds__(256, 3)
kB(const float* __restrict__ queries, const float* __restrict__ qmask,
   const float* __restrict__ bq, const float* __restrict__ bm,
   const short8* __restrict__ WfQ, const short8* __restrict__ WfM,
   const float* __restrict__ KV, const float* __restrict__ Ksum,
   float* __restrict__ out) {
  extern __shared__ char lds[];
  char* bufQ = lds + KB_Q;
  char* ldsO = lds + KB_O;
  float* ldsM = (float*)(lds + KB_M);
  float* ldsS = (float*)(lds + KB_S);
  float* ldsBq = (float*)(lds + KB_BQ);
  const int tid = threadIdx.x, w = tid >> 6, lane = tid & 63, lo = lane & 31, kg = lane >> 5;
  const int blk = blockIdx.x, b = blockIdx.y;
  const size_t base = ((size_t)b * S_ + blk * 32) * D_;

  issue_tile(queries + base, bufQ, w, lane);  // Q in flight (zero VGPR)

  ldsS[tid] = Ksum[b * 256 + tid];
  ldsBq[tid] = bq[tid];
  if (tid < 32) ldsM[tid] = qmask[(size_t)b * S_ + blk * 32 + tid];
  const float bm0 = bm[w * 64 + lo], bm1 = bm[w * 64 + 32 + lo];

  // hoist KV fragments (A-frag: rows m = lo, k = d) for this wave's two heads
  short8 kvf[2][2];
#pragma unroll
  for (int hh = 0; hh < 2; ++hh)
#pragma unroll
    for (int ksd = 0; ksd < 2; ++ksd) {
      const float* p = KV + (((size_t)b * H_ + 2 * w + hh) * 32 + lo) * 32 + ksd * 16 + kg * 8;
      float4 x0 = *(const float4*)p, x1 = *(const float4*)(p + 4);
      union { unsigned u[4]; short8 s8; } t;
      t.u[0] = pack2(x0.x, x0.y); t.u[1] = pack2(x0.z, x0.w);
      t.u[2] = pack2(x1.x, x1.y); t.u[3] = pack2(x1.z, x1.w);
      kvf[hh][ksd] = t.s8;
    }

  __syncthreads();  // Q arrived + smalls visible

  // ---- Q projection FLIPPED: D[o][tok], o rows, tok cols = lo ----
  f32x16 qa[2];
#pragma unroll
  for (int At = 0; At < 2; ++At)
#pragma unroll
    for (int i = 0; i < 16; ++i) qa[At][i] = 0.f;
#pragma unroll 4
  for (int ks = 0; ks < 16; ++ks) {
    const int g = 2 * ks + kg;
    short8 a0 = WfQ[g * 256 + w * 64 + lo];
    short8 a1 = WfQ[g * 256 + w * 64 + 32 + lo];
    short8 bx = ld_frag_f32(bufQ, lo, g);
    qa[0] = __builtin_amdgcn_mfma_f32_32x32x16_bf16(a0, bx, qa[0], 0, 0, 0);
    qa[1] = __builtin_amdgcn_mfma_f32_32x32x16_bf16(a1, bx, qa[1], 0, 0, 0);
  }

  // epilogue: bias + elu+1 + qmask -> words; per-head Z via 32-term dot
  unsigned Wq_[2][4][2];
  float inv_[2];
  const float qm = ldsM[lo];
#pragma unroll
  for (int At = 0; At < 2; ++At) {
    float z = 0.f;
#pragma unroll
    for (int q = 0; q < 4; ++q) {
      float vv[4];
#pragma unroll
      for (int c = 0; c < 4; ++c) {
        const int o = w * 64 + At * 32 + 8 * q + 4 * kg + c;
        float f = qa[At][4 * q + c] + ldsBq[o];
        f = f > 0.f ? f + 1.f : __expf(f);
        f *= qm;
        z += f * ldsS[o];
        vv[c] = f;
      }
      Wq_[At][q][0] = pack2(vv[0], vv[1]);
      Wq_[At][q][1] = pack2(vv[2], vv[3]);
    }
    const float zf = z + __shfl_xor(z, 32);
    inv_[At] = 1.0f / (zf + EPS_);
  }

  // ---- num = KV x qf (D[m][tok]); vo = num*inv -> ldsO bf16 chunks ----
#pragma unroll
  for (int hh = 0; hh < 2; ++hh) {
    const int h = 2 * w + hh;
    f32x16 pn;
#pragma unroll
    for (int i = 0; i < 16; ++i) pn[i] = 0.f;
#pragma unroll
    for (int ksd = 0; ksd < 2; ++ksd) {
      short8 qf = mk_frag(Wq_[hh][2 * ksd][0], Wq_[hh][2 * ksd][1],
                          Wq_[hh][2 * ksd + 1][0], Wq_[hh][2 * ksd + 1][1], kg);
      pn = __builtin_amdgcn_mfma_f32_32x32x16_bf16(kvf[hh][ksd], qf, pn, 0, 0, 0);
    }
    const float inv = inv_[hh];
#pragma unroll
    for (int q = 0; q < 4; ++q)
      *(ushort4*)(ldsO + ((h * 4 + q) * 32 + lo) * 16 + kg * 8) =
          make_ushort4(f2bf(pn[4 * q + 0] * inv), f2bf(pn[4 * q + 1] * inv),
                       f2bf(pn[4 * q + 2] * inv), f2bf(pn[4 * q + 3] * inv));
  }
  __syncthreads();  // voF complete (cross-wave reads next)

  // ---- out = vo @ Wm^T + bm ----
  f32x16 oa[2];
#pragma unroll
  for (int nt = 0; nt < 2; ++nt)
#pragma unroll
    for (int i = 0; i < 16; ++i) oa[nt][i] = 0.f;
#pragma unroll 4
  for (int ks = 0; ks < 16; ++ks) {
    const int g = 2 * ks + kg;
    short8 av = *(const short8*)(ldsO + (g * 32 + lo) * 16);
    short8 b0 = WfM[g * 256 + w * 64 + lo];
    short8 b1 = WfM[g * 256 + w * 64 + 32 + lo];
    oa[0] = __builtin_amdgcn_mfma_f32_32x32x16_bf16(av, b0, oa[0], 0, 0, 0);
    oa[1] = __builtin_amdgcn_mfma_f32_32x32x16_bf16(av, b1, oa[1], 0, 0, 0);
  }
#pragma unroll
  for (int nt = 0; nt < 2; ++nt) {
    const float bias = nt ? bm1 : bm0;
    const int o = w * 64 + nt * 32 + lo;
    float* dst = out + ((size_t)b * S_ + blk * 32) * D_ + o;
#pragma unroll
    for (int r = 0; r < 16; ++r) {
      const int tok = (r & 3) + 8 * (r >> 2) + 4 * kg;
      dst[(size_t)tok * D_] = oa[nt][r] + bias;
    }
  }
}

extern "C" void kernel_launch(void* const* d_in, const int* in_sizes, int n_in,
                              void* d_out, int out_size, void* d_ws, size_t ws_size,
                              hipStream_t stream) {
  const float* queries = (const float*)d_in[0];
  const float* keys    = (const float*)d_in[1];
  const float* values  = (const float*)d_in[2];
  const float* qmask   = (const float*)d_in[3];
  const float* kmask   = (const float*)d_in[4];
  const float* Wq = (const float*)d_in[5];
  const float* bq = (const float*)d_in[6];
  const float* Wk = (const float*)d_in[7];
  const float* bk = (const float*)d_in[8];
  const float* Wv = (const float*)d_in[9];
  const float* bv = (const float*)d_in[10];
  const float* Wm = (const float*)d_in[11];
  const float* bm = (const float*)d_in[12];
  float* out = (float*)d_out;

  char* ws = (char*)d_ws;
  unsigned short* Wf = (unsigned short*)ws;          // 512KB
  float* KV   = (float*)(ws + 524288);               // 256KB
  float* Ksum = (float*)(ws + 786432);               // 8KB
  float* kvpart = (float*)(ws + 1048576);            // 16MB
  float* kspart = (float*)(ws + 1048576 + 16777216); // 512KB
  const size_t need = 1048576 + 16777216 + 524288;
  const int use_atomic = (ws_size < need) ? 1 : 0;

  (void)hipFuncSetAttribute(reinterpret_cast<const void*>(kA),
                            hipFuncAttributeMaxDynamicSharedMemorySize, KA_BYTES);
  (void)hipFuncSetAttribute(reinterpret_cast<const void*>(kB),
                            hipFuncAttributeMaxDynamicSharedMemorySize, KB_BYTES);

  kPrep<<<128, 256, 0, stream>>>(Wq, Wk, Wv, Wm, Wf);
  if (use_atomic) (void)hipMemsetAsync(ws + 524288, 0, 262144 + 8192, stream);

  const short8* Wf8 = (const short8*)Wf;
  kA<<<dim3(64, B_), 256, KA_BYTES, stream>>>(keys, values, kmask, bk, bv,
      Wf8 + (size_t)1 * 8192, Wf8 + (size_t)2 * 8192, kvpart, kspart, KV, Ksum, use_atomic);
  if (!use_atomic) kR<<<264, 256, 0, stream>>>(kvpart, kspart, KV, Ksum);
  kB<<<dim3(256, B_), 256, KB_BYTES, stream>>>(queries, qmask, bq, bm,
      Wf8, Wf8 + (size_t)3 * 8192, KV, Ksum, out);
}